// Round 3
// baseline (1236.491 us; speedup 1.0000x reference)
//
#include <hip/hip_runtime.h>

// ---------------------------------------------------------------------------
// PoetryModel: embed -> x_gates GEMM -> LSTM(128 steps) -> classifier GEMM
//              -> log_softmax over V -> out (B, V, S) f32
// B=64 S=128 V=8000 E=256 H=512 G=4H=2048
// ---------------------------------------------------------------------------

using u16   = unsigned short;
using u32   = unsigned int;
using u16x8 = __attribute__((ext_vector_type(8))) u16;
using bf16x8 = __attribute__((ext_vector_type(8))) __bf16;
using f32x4 = __attribute__((ext_vector_type(4))) float;

#define NB   64        // batch
#define NS   128       // seq len
#define NV   8000      // vocab
#define NVP  8192      // vocab padded to tile
#define NE   256       // embed dim
#define NH   512       // hidden
#define NG   2048      // 4*H
#define NBS  8192      // B*S
#define OUT_BSTRIDE 1024000   // V*S
#define XG_SSTRIDE  131072    // G*B

__device__ inline u16 f2bf(float f) {
    unsigned x = __builtin_bit_cast(unsigned, f);
    unsigned r = (x + 0x7FFFu + ((x >> 16) & 1u)) >> 16;
    return (u16)r;
}

__device__ inline bf16x8 ld_frag(const u16* p) {
    u16x8 v = *(const u16x8*)p;
    return __builtin_bit_cast(bf16x8, v);
}

// load that bypasses L1+L2 (reads the LLC coherence point directly)
__device__ inline u32 load_llc(const u32* p) {
    u32 v;
    asm volatile("global_load_dword %0, %1, off sc0 sc1\n\t"
                 "s_waitcnt vmcnt(0)"
                 : "=v"(v) : "v"(p) : "memory");
    return v;
}

// ---------------------------------------------------------------- converts
__global__ void cvt_bf16(const float* __restrict__ s, u16* __restrict__ d, int n8) {
    const float4* s4 = (const float4*)s;
    for (int i = blockIdx.x * blockDim.x + threadIdx.x; i < n8;
         i += gridDim.x * blockDim.x) {
        float4 a = s4[2 * i], b = s4[2 * i + 1];
        u16x8 o;
        o[0] = f2bf(a.x); o[1] = f2bf(a.y); o[2] = f2bf(a.z); o[3] = f2bf(a.w);
        o[4] = f2bf(b.x); o[5] = f2bf(b.y); o[6] = f2bf(b.z); o[7] = f2bf(b.w);
        ((u16x8*)d)[i] = o;
    }
}

// ------------------------------------------------- K1: x_gates = x @ W_ih^T
__global__ __launch_bounds__(256) void k1_xgates(
    const u16* __restrict__ Wih, const u16* __restrict__ emb,
    const int* __restrict__ toks,
    const float* __restrict__ bih, const float* __restrict__ bhh,
    float* __restrict__ xg)
{
    __shared__ u16x8 Al8[512];   // [128][32] bf16
    __shared__ u16x8 Bl8[512];
    u16* Al = (u16*)Al8;
    u16* Bl = (u16*)Bl8;

    const int t = threadIdx.x;
    const int lane = t & 63, w = t >> 6;
    const int wm = w >> 1, wn = w & 1;
    const int gtile = blockIdx.y * 128, mtile = blockIdx.x * 128;

    const int r0 = t >> 2, r1 = r0 + 64, q = t & 3;
    const int m0 = mtile + r0, m1 = mtile + r1;
    const int tok0 = toks[(m0 & 63) * NS + (m0 >> 6)];
    const int tok1 = toks[(m1 & 63) * NS + (m1 >> 6)];

    f32x4 acc[4][4];
    for (int i = 0; i < 4; ++i)
        for (int j = 0; j < 4; ++j) acc[i][j] = {0.f, 0.f, 0.f, 0.f};

    const int kc8 = (lane >> 4) * 8;
    for (int kk = 0; kk < 8; ++kk) {
        const int k0 = kk * 32;
        *(u16x8*)&Al[t * 8]         = *(const u16x8*)&Wih[(gtile + r0) * NE + k0 + q * 8];
        *(u16x8*)&Al[(t + 256) * 8] = *(const u16x8*)&Wih[(gtile + r1) * NE + k0 + q * 8];
        *(u16x8*)&Bl[t * 8]         = *(const u16x8*)&emb[tok0 * NE + k0 + q * 8];
        *(u16x8*)&Bl[(t + 256) * 8] = *(const u16x8*)&emb[tok1 * NE + k0 + q * 8];
        __syncthreads();
        bf16x8 af[4], bf[4];
        #pragma unroll
        for (int i = 0; i < 4; ++i) {
            af[i] = ld_frag(&Al[(wm * 64 + i * 16 + (lane & 15)) * 32 + kc8]);
            bf[i] = ld_frag(&Bl[(wn * 64 + i * 16 + (lane & 15)) * 32 + kc8]);
        }
        #pragma unroll
        for (int fi = 0; fi < 4; ++fi)
            #pragma unroll
            for (int fj = 0; fj < 4; ++fj)
                acc[fi][fj] = __builtin_amdgcn_mfma_f32_16x16x32_bf16(
                    af[fi], bf[fj], acc[fi][fj], 0, 0, 0);
        __syncthreads();
    }

    #pragma unroll
    for (int fi = 0; fi < 4; ++fi) {
        const int g0 = gtile + wm * 64 + fi * 16 + ((lane >> 4) << 2);
        const float4 v1 = *(const float4*)&bih[g0];
        const float4 v2 = *(const float4*)&bhh[g0];
        float badd[4] = {v1.x + v2.x, v1.y + v2.y, v1.z + v2.z, v1.w + v2.w};
        #pragma unroll
        for (int fj = 0; fj < 4; ++fj) {
            const int m = mtile + wn * 64 + fj * 16 + (lane & 15);
            const int b = m & 63, s = m >> 6;
            float* dst = &xg[s * XG_SSTRIDE + b];
            #pragma unroll
            for (int r = 0; r < 4; ++r)
                dst[(g0 + r) * 64] = acc[fi][fj][r] + badd[r];
        }
    }
}

// --------------------------------------------------------- K2: LSTM (persistent)
// 64 blocks x 512 thr. Block owns 8 hidden units; W_hh fragments register-
// resident. B-row mapping j -> (gate=j&3, unit=j>>2) so a 4x4 lane-group
// shfl transpose puts all 4 gates of one (batch,unit) into one lane:
// nonlinearity fully in-register, no LDS, 1 syncthreads pre-flag + 1 post-wait.
// Sync: per-block flags; poll via sc0/sc1 (cache-bypassing) loads; single
// ACQUIRE load after success supplies the buffer_inv for the h reloads.
#define LSTM_NBLK 64

__global__ __launch_bounds__(512, 2) void k2_lstm(
    const u16* __restrict__ Whh,     // [2048][512] bf16
    const float* __restrict__ xg,    // [S][G][B]
    u16* __restrict__ hbuf,          // [2][64][512] bf16 (zeroed)
    u16* __restrict__ hidden,        // [8192][512] bf16
    u32* __restrict__ flags)         // [64] (zeroed)
{
    const int t = threadIdx.x, lane = t & 63, w = t >> 6;
    const int wm = w >> 1, wn = w & 1;        // wm: batch quarter, wn: unit half
    const int u0 = blockIdx.x * 8;
    const int kc8 = (lane >> 4) * 8;
    const int j = lane & 15;
    // B row j -> gate (j&3) of unit (wn*4 + (j>>2))
    const int gj = (j & 3) * 512 + u0 + wn * 4 + (j >> 2);

    // W_hh fragments resident in registers (64 VGPRs), pinned via opaque asm.
    bf16x8 bw[16];
    #pragma unroll
    for (int kk = 0; kk < 16; ++kk)
        bw[kk] = ld_frag(&Whh[gj * NH + kk * 32 + kc8]);
    #pragma unroll
    for (int kk = 0; kk < 16; ++kk) {
        f32x4 wv = __builtin_bit_cast(f32x4, bw[kk]);
        asm volatile("" : "+v"(wv));
        bw[kk] = __builtin_bit_cast(bf16x8, wv);
    }

    const int p    = lane & 3;                  // within 4-lane transpose group
    const int arow = wm * 16 + j;               // A (h) row = batch
    const int mb   = wm * 16 + ((lane >> 4) << 2);
    const int bat  = mb + p;                    // this lane's batch after transpose
    const int un   = u0 + wn * 4 + (j >> 2);    // this lane's unit
    const bool store_lane = ((lane & 4) == 0);  // even-unit lanes store pairs
    float creg = 0.f;

    float4 xv = *(const float4*)&xg[gj * 64 + mb];   // step 0

    for (int step = 0; step < NS; ++step) {
        // prefetch next step's xv at top: latency hides under MFMA phase
        float4 xvn;
        if (step + 1 < NS)
            xvn = *(const float4*)&xg[(step + 1) * XG_SSTRIDE + gj * 64 + mb];

        const u16* hcur = hbuf + (step & 1) * (NB * NH);
        f32x4 acc[4];
        #pragma unroll
        for (int i = 0; i < 4; ++i) acc[i] = {0.f, 0.f, 0.f, 0.f};
        #pragma unroll
        for (int kk = 0; kk < 16; ++kk) {
            bf16x8 a0 = ld_frag(&hcur[arow * NH + kk * 32 + kc8]);
            acc[kk & 3] = __builtin_amdgcn_mfma_f32_16x16x32_bf16(
                a0, bw[kk], acc[kk & 3], 0, 0, 0);
        }
        float v[4];
        #pragma unroll
        for (int r = 0; r < 4; ++r)
            v[r] = acc[0][r] + acc[1][r] + acc[2][r] + acc[3][r] + (&xv.x)[r];

        // 4x4 transpose across lane group {p} x element {r}
        float tb[4];
        #pragma unroll
        for (int q2 = 0; q2 < 4; ++q2) tb[q2] = __shfl_xor(v[q2 ^ 2], 2);
        #pragma unroll
        for (int q2 = 0; q2 < 4; ++q2) v[q2] = (((q2 ^ p) & 2) ? tb[q2] : v[q2]);
        #pragma unroll
        for (int q2 = 0; q2 < 4; ++q2) tb[q2] = __shfl_xor(v[q2 ^ 1], 1);
        #pragma unroll
        for (int q2 = 0; q2 < 4; ++q2) v[q2] = (((q2 ^ p) & 1) ? tb[q2] : v[q2]);
        // v = {i, f, g~, o} for (bat, un)

        float i_ = 1.f / (1.f + __expf(-v[0]));
        float f_ = 1.f / (1.f + __expf(-v[1]));
        float e2 = __expf(2.f * v[2]);
        float g_ = 1.f - 2.f / (e2 + 1.f);
        float o_ = 1.f / (1.f + __expf(-v[3]));
        creg = f_ * creg + i_ * g_;
        float e2c = __expf(2.f * creg);
        float h = o_ * (1.f - 2.f / (e2c + 1.f));

        u32 hb = f2bf(h);
        u32 other = __shfl_xor(hb, 4);          // partner holds unit un^1
        if (store_lane) {
            u32 pairv = hb | (other << 16);
            __hip_atomic_store(
                (u32*)&hbuf[((step & 1) ^ 1) * (NB * NH) + bat * NH + un],
                pairv, __ATOMIC_RELAXED, __HIP_MEMORY_SCOPE_AGENT);
            *(u32*)&hidden[(bat * NS + step) * NH + un] = pairv;
        }
        xv = xvn;
        __syncthreads();   // all waves' stores drained (vmcnt 0) -> LLC visible

        if (step + 1 < NS) {
            if (t == 0)
                __hip_atomic_store(&flags[blockIdx.x], (u32)(step + 1),
                                   __ATOMIC_RELAXED, __HIP_MEMORY_SCOPE_AGENT);
            if (t < 64) {
                while (load_llc(&flags[t]) < (u32)(step + 1))
                    __builtin_amdgcn_s_sleep(1);
                u32 fv = __hip_atomic_load(&flags[t], __ATOMIC_ACQUIRE,
                                           __HIP_MEMORY_SCOPE_AGENT);
                asm volatile("" :: "v"(fv));   // keep the acquire (buffer_inv) live
            }
            __syncthreads();
        }
    }
}

// ------------------------------------- K3: logits = hidden @ W_cls^T + b_cls
__global__ __launch_bounds__(256) void k3_cls(
    const u16* __restrict__ Wc, const u16* __restrict__ hid,
    const float* __restrict__ bcls,
    float* __restrict__ out, float* __restrict__ lse)
{
    __shared__ u16x8 Al8[512];
    __shared__ u16x8 Bl8[512];
    __shared__ float red[2][128];
    u16* Al = (u16*)Al8;
    u16* Bl = (u16*)Bl8;

    const int t = threadIdx.x;
    const int lane = t & 63, w = t >> 6;
    const int wm = w >> 1, wn = w & 1;
    const int vtile = blockIdx.y * 128, mtile = blockIdx.x * 128;

    const int r0 = t >> 2, r1 = r0 + 64, q = t & 3;

    f32x4 acc[4][4];
    for (int i = 0; i < 4; ++i)
        for (int j2 = 0; j2 < 4; ++j2) acc[i][j2] = {0.f, 0.f, 0.f, 0.f};

    const int kc8 = (lane >> 4) * 8;
    for (int kk = 0; kk < 16; ++kk) {
        const int k0 = kk * 32;
        *(u16x8*)&Al[t * 8]         = *(const u16x8*)&Wc[(vtile + r0) * NH + k0 + q * 8];
        *(u16x8*)&Al[(t + 256) * 8] = *(const u16x8*)&Wc[(vtile + r1) * NH + k0 + q * 8];
        *(u16x8*)&Bl[t * 8]         = *(const u16x8*)&hid[(mtile + r0) * NH + k0 + q * 8];
        *(u16x8*)&Bl[(t + 256) * 8] = *(const u16x8*)&hid[(mtile + r1) * NH + k0 + q * 8];
        __syncthreads();
        bf16x8 af[4], bf[4];
        #pragma unroll
        for (int i = 0; i < 4; ++i) {
            af[i] = ld_frag(&Al[(wm * 64 + i * 16 + (lane & 15)) * 32 + kc8]);
            bf[i] = ld_frag(&Bl[(wn * 64 + i * 16 + (lane & 15)) * 32 + kc8]);
        }
        #pragma unroll
        for (int fi = 0; fi < 4; ++fi)
            #pragma unroll
            for (int fj = 0; fj < 4; ++fj)
                acc[fi][fj] = __builtin_amdgcn_mfma_f32_16x16x32_bf16(
                    af[fi], bf[fj], acc[fi][fj], 0, 0, 0);
        __syncthreads();
    }

    float lsum[4] = {0.f, 0.f, 0.f, 0.f};
    #pragma unroll
    for (int fi = 0; fi < 4; ++fi) {
        const int v0 = vtile + wm * 64 + fi * 16 + ((lane >> 4) << 2);
        const bool vok = (v0 < NV);
        float4 bc = {0.f, 0.f, 0.f, 0.f};
        if (vok) bc = *(const float4*)&bcls[v0];
        #pragma unroll
        for (int fj = 0; fj < 4; ++fj) {
            const int m = mtile + wn * 64 + fj * 16 + (lane & 15);
            const int b = m >> 7, s = m & 127;
            if (vok) {
                float* dst = &out[b * OUT_BSTRIDE + v0 * NS + s];
                float e = 0.f;
                #pragma unroll
                for (int r = 0; r < 4; ++r) {
                    float lg = acc[fi][fj][r] + (&bc.x)[r];
                    dst[r * NS] = lg;
                    e += __expf(lg);
                }
                lsum[fj] += e;
            }
        }
    }
    #pragma unroll
    for (int fj = 0; fj < 4; ++fj) {
        lsum[fj] += __shfl_xor(lsum[fj], 16);
        lsum[fj] += __shfl_xor(lsum[fj], 32);
    }
    if (lane < 16) {
        #pragma unroll
        for (int fj = 0; fj < 4; ++fj)
            red[wm][wn * 64 + fj * 16 + lane] = lsum[fj];
    }
    __syncthreads();
    if (t < 128) {
        const int m = mtile + t;
        atomicAdd(&lse[m], red[0][t] + red[1][t]);
    }
}

// ------------------------------------------------------------- K4/K5 epilogue
__global__ void k4_log(const float* __restrict__ lse, float* __restrict__ ll) {
    int i = blockIdx.x * 256 + threadIdx.x;
    if (i < NBS) ll[i] = logf(lse[i]);
}

__global__ void k5_norm(float* __restrict__ out, const float* __restrict__ ll) {
    const int total4 = NB * NV * NS / 4;   // 16,384,000
    float4* o4 = (float4*)out;
    for (int i = blockIdx.x * blockDim.x + threadIdx.x; i < total4;
         i += gridDim.x * blockDim.x) {
        const int i4 = i * 4;
        const int b = i4 / OUT_BSTRIDE;
        const int s = (i4 - b * OUT_BSTRIDE) & 127;
        float4 v = o4[i];
        const float4 l = *(const float4*)&ll[b * NS + s];
        v.x -= l.x; v.y -= l.y; v.z -= l.z; v.w -= l.w;
        o4[i] = v;
    }
}

// ---------------------------------------------------------------------------
extern "C" void kernel_launch(void* const* d_in, const int* in_sizes, int n_in,
                              void* d_out, int out_size, void* d_ws, size_t ws_size,
                              hipStream_t stream) {
    const int*   toks   = (const int*)d_in[0];
    const float* emb_f  = (const float*)d_in[1];
    const float* Wih_f  = (const float*)d_in[2];
    const float* Whh_f  = (const float*)d_in[3];
    const float* bih    = (const float*)d_in[4];
    const float* bhh    = (const float*)d_in[5];
    const float* Wcls_f = (const float*)d_in[6];
    const float* bcls   = (const float*)d_in[7];
    float* out = (float*)d_out;
    char*  ws  = (char*)d_ws;

    // workspace layout (bytes)
    float* lse    = (float*)(ws + 0);          // 32768
    float* loglse = (float*)(ws + 32768);      // 32768
    u32*   flags  = (u32*)(ws + 65536);        // 256
    u16*   hbuf   = (u16*)(ws + 65792);        // 131072
    u16*   embb   = (u16*)(ws + 196864);       // 4,096,000
    u16*   wihb   = (u16*)(ws + 4292864);      // 1,048,576
    u16*   whhb   = (u16*)(ws + 5341440);      // 2,097,152
    u16*   wclsb  = (u16*)(ws + 7438592);      // 8,388,608 (padded 8192 rows)
    u16*   hidden = (u16*)(ws + 15827200);     // 8,388,608

    // x_gates f32 [S][G][B] lives in d_out scratch (16.8M floats < 65.5M)
    float* xg = out;

    hipMemsetAsync(ws, 0, 196864, stream);     // lse + loglse + flags + hbuf
    hipMemsetAsync((char*)wclsb + NV * NH * 2, 0, (NVP - NV) * NH * 2, stream);

    cvt_bf16<<<1024, 256, 0, stream>>>(emb_f,  embb,  NV * NE / 8);
    cvt_bf16<<<256,  256, 0, stream>>>(Wih_f,  wihb,  NG * NE / 8);
    cvt_bf16<<<512,  256, 0, stream>>>(Whh_f,  whhb,  NG * NH / 8);
    cvt_bf16<<<1024, 256, 0, stream>>>(Wcls_f, wclsb, NV * NH / 8);

    k1_xgates<<<dim3(64, 16), 256, 0, stream>>>(wihb, embb, toks, bih, bhh, xg);
    k2_lstm<<<LSTM_NBLK, 512, 0, stream>>>(whhb, xg, hbuf, hidden, flags);
    k3_cls<<<dim3(64, 64), 256, 0, stream>>>(wclsb, hidden, bcls, out, lse);
    k4_log<<<32, 256, 0, stream>>>(lse, loglse);
    k5_norm<<<2048, 256, 0, stream>>>(out, loglse);
}

// Round 4
// 668.501 us; speedup vs baseline: 1.8496x; 1.8496x over previous
//
#include <hip/hip_runtime.h>

// ---------------------------------------------------------------------------
// PoetryModel: embed -> x_gates GEMM -> LSTM(128 steps) -> classifier GEMM
//              -> log_softmax over V -> out (B, V, S) f32
// B=64 S=128 V=8000 E=256 H=512 G=4H=2048
// ---------------------------------------------------------------------------

using u16   = unsigned short;
using u32   = unsigned int;
using u16x8 = __attribute__((ext_vector_type(8))) u16;
using bf16x8 = __attribute__((ext_vector_type(8))) __bf16;
using f32x4 = __attribute__((ext_vector_type(4))) float;

#define NB   64        // batch
#define NS   128       // seq len
#define NV   8000      // vocab
#define NVP  8192      // vocab padded to tile
#define NE   256       // embed dim
#define NH   512       // hidden
#define NG   2048      // 4*H
#define NBS  8192      // B*S
#define OUT_BSTRIDE 1024000   // V*S
#define XG_SSTRIDE  131072    // G*B

__device__ inline u16 f2bf(float f) {
    unsigned x = __builtin_bit_cast(unsigned, f);
    unsigned r = (x + 0x7FFFu + ((x >> 16) & 1u)) >> 16;
    return (u16)r;
}

__device__ inline bf16x8 ld_frag(const u16* p) {
    u16x8 v = *(const u16x8*)p;
    return __builtin_bit_cast(bf16x8, v);
}

// LLC-coherent ops: bypass L1+L2, never create/consume dirty L2 lines.
__device__ inline u32 load_llc(const u32* p) {
    u32 v;
    asm volatile("global_load_dword %0, %1, off sc0 sc1\n\t"
                 "s_waitcnt vmcnt(0)"
                 : "=v"(v) : "v"(p) : "memory");
    return v;
}
__device__ inline f32x4 load_llc16(const void* p) {
    f32x4 v;
    asm volatile("global_load_dwordx4 %0, %1, off sc0 sc1\n\t"
                 "s_waitcnt vmcnt(0)"
                 : "=v"(v) : "v"(p) : "memory");
    return v;
}
__device__ inline void store_llc(u32* p, u32 v) {
    asm volatile("global_store_dword %0, %1, off sc0 sc1"
                 :: "v"(p), "v"(v) : "memory");
}

// 4x4 transpose across lane quad {p} x element {r} (verified round 3)
__device__ inline void quad_transpose(float v[4], int p) {
    float tb[4];
    #pragma unroll
    for (int q2 = 0; q2 < 4; ++q2) tb[q2] = __shfl_xor(v[q2 ^ 2], 2);
    #pragma unroll
    for (int q2 = 0; q2 < 4; ++q2) v[q2] = (((q2 ^ p) & 2) ? tb[q2] : v[q2]);
    #pragma unroll
    for (int q2 = 0; q2 < 4; ++q2) tb[q2] = __shfl_xor(v[q2 ^ 1], 1);
    #pragma unroll
    for (int q2 = 0; q2 < 4; ++q2) v[q2] = (((q2 ^ p) & 1) ? tb[q2] : v[q2]);
}

__device__ inline float lstm_cell(const float v[4], float& c) {
    float i_ = 1.f / (1.f + __expf(-v[0]));
    float f_ = 1.f / (1.f + __expf(-v[1]));
    float e2 = __expf(2.f * v[2]);
    float g_ = 1.f - 2.f / (e2 + 1.f);
    float o_ = 1.f / (1.f + __expf(-v[3]));
    c = f_ * c + i_ * g_;
    float e2c = __expf(2.f * c);
    return o_ * (1.f - 2.f / (e2c + 1.f));
}

// ---------------------------------------------------------------- converts
__global__ void cvt_bf16(const float* __restrict__ s, u16* __restrict__ d, int n8) {
    const float4* s4 = (const float4*)s;
    for (int i = blockIdx.x * blockDim.x + threadIdx.x; i < n8;
         i += gridDim.x * blockDim.x) {
        float4 a = s4[2 * i], b = s4[2 * i + 1];
        u16x8 o;
        o[0] = f2bf(a.x); o[1] = f2bf(a.y); o[2] = f2bf(a.z); o[3] = f2bf(a.w);
        o[4] = f2bf(b.x); o[5] = f2bf(b.y); o[6] = f2bf(b.z); o[7] = f2bf(b.w);
        ((u16x8*)d)[i] = o;
    }
}

// ------------------------------------------------- K1: x_gates = x @ W_ih^T
__global__ __launch_bounds__(256) void k1_xgates(
    const u16* __restrict__ Wih, const u16* __restrict__ emb,
    const int* __restrict__ toks,
    const float* __restrict__ bih, const float* __restrict__ bhh,
    float* __restrict__ xg)
{
    __shared__ u16x8 Al8[512];   // [128][32] bf16
    __shared__ u16x8 Bl8[512];
    u16* Al = (u16*)Al8;
    u16* Bl = (u16*)Bl8;

    const int t = threadIdx.x;
    const int lane = t & 63, w = t >> 6;
    const int wm = w >> 1, wn = w & 1;
    const int gtile = blockIdx.y * 128, mtile = blockIdx.x * 128;

    const int r0 = t >> 2, r1 = r0 + 64, q = t & 3;
    const int m0 = mtile + r0, m1 = mtile + r1;
    const int tok0 = toks[(m0 & 63) * NS + (m0 >> 6)];
    const int tok1 = toks[(m1 & 63) * NS + (m1 >> 6)];

    f32x4 acc[4][4];
    for (int i = 0; i < 4; ++i)
        for (int j = 0; j < 4; ++j) acc[i][j] = {0.f, 0.f, 0.f, 0.f};

    const int kc8 = (lane >> 4) * 8;
    for (int kk = 0; kk < 8; ++kk) {
        const int k0 = kk * 32;
        *(u16x8*)&Al[t * 8]         = *(const u16x8*)&Wih[(gtile + r0) * NE + k0 + q * 8];
        *(u16x8*)&Al[(t + 256) * 8] = *(const u16x8*)&Wih[(gtile + r1) * NE + k0 + q * 8];
        *(u16x8*)&Bl[t * 8]         = *(const u16x8*)&emb[tok0 * NE + k0 + q * 8];
        *(u16x8*)&Bl[(t + 256) * 8] = *(const u16x8*)&emb[tok1 * NE + k0 + q * 8];
        __syncthreads();
        bf16x8 af[4], bf[4];
        #pragma unroll
        for (int i = 0; i < 4; ++i) {
            af[i] = ld_frag(&Al[(wm * 64 + i * 16 + (lane & 15)) * 32 + kc8]);
            bf[i] = ld_frag(&Bl[(wn * 64 + i * 16 + (lane & 15)) * 32 + kc8]);
        }
        #pragma unroll
        for (int fi = 0; fi < 4; ++fi)
            #pragma unroll
            for (int fj = 0; fj < 4; ++fj)
                acc[fi][fj] = __builtin_amdgcn_mfma_f32_16x16x32_bf16(
                    af[fi], bf[fj], acc[fi][fj], 0, 0, 0);
        __syncthreads();
    }

    #pragma unroll
    for (int fi = 0; fi < 4; ++fi) {
        const int g0 = gtile + wm * 64 + fi * 16 + ((lane >> 4) << 2);
        const float4 v1 = *(const float4*)&bih[g0];
        const float4 v2 = *(const float4*)&bhh[g0];
        float badd[4] = {v1.x + v2.x, v1.y + v2.y, v1.z + v2.z, v1.w + v2.w};
        #pragma unroll
        for (int fj = 0; fj < 4; ++fj) {
            const int m = mtile + wn * 64 + fj * 16 + (lane & 15);
            const int b = m & 63, s = m >> 6;
            float* dst = &xg[s * XG_SSTRIDE + b];
            #pragma unroll
            for (int r = 0; r < 4; ++r)
                dst[(g0 + r) * 64] = acc[fi][fj][r] + badd[r];
        }
    }
}

// --------------------------------------------------------- K2: LSTM (persistent)
// 64 blocks = 8 batch-groups (bg) x 8 unit-slices (ug). Block owns 8 batches x
// 64 units: 256 gate rows register-resident (128 VGPR/lane). Sync only within
// the 8-block batch-group: per-block flag on its OWN 128B line, all h/flag
// traffic explicitly LLC-coherent (sc0 sc1) -> no buffer_inv, no dirty-L2
// staleness across graph replays. h_t staged once to LDS per block.
#define LSTM_NBLK 64

__global__ __launch_bounds__(512, 2) void k2_lstm(
    const u16* __restrict__ Whh,     // [2048][512] bf16
    const float* __restrict__ xg,    // [S][G][B]
    u16* __restrict__ hbuf,          // [2][64][512] bf16 (zeroed)
    u16* __restrict__ hidden,        // [8192][512] bf16
    u32* __restrict__ flags)         // [64] on 128B-strided lines (zeroed)
{
    __shared__ __align__(16) u16 hl[16 * 520];   // [16 rows][512+8 pad] bf16

    const int t = threadIdx.x, lane = t & 63, w = t >> 6;   // 8 waves
    const int bg = blockIdx.x >> 3, ug = blockIdx.x & 7;
    const int j = lane & 15, kg = lane >> 4;
    const int kc8 = kg * 8;

    // wave w owns units ug*64 + w*8 .. +7, all 4 gates (2 MFMA N-tiles).
    // tile n, col j -> gate (j&3), unit w*8 + n*4 + (j>>2)
    const int ubase = ug * 64 + w * 8;
    const int grow0 = (j & 3) * 512 + ubase + (j >> 2);
    const int grow1 = grow0 + 4;

    bf16x8 bw0[16], bw1[16];
    #pragma unroll
    for (int kk = 0; kk < 16; ++kk) {
        bw0[kk] = ld_frag(&Whh[grow0 * NH + kk * 32 + kc8]);
        bw1[kk] = ld_frag(&Whh[grow1 * NH + kk * 32 + kc8]);
    }
    #pragma unroll
    for (int kk = 0; kk < 16; ++kk) {     // pin weights in VGPRs
        f32x4 w0 = __builtin_bit_cast(f32x4, bw0[kk]);
        f32x4 w1 = __builtin_bit_cast(f32x4, bw1[kk]);
        asm volatile("" : "+v"(w0), "+v"(w1));
        bw0[kk] = __builtin_bit_cast(bf16x8, w0);
        bw1[kk] = __builtin_bit_cast(bf16x8, w1);
    }

    // zero LDS batch-pad rows 8..15 once (A rows 8..15 read zeros)
    {
        u16x8 z = {0, 0, 0, 0, 0, 0, 0, 0};
        *(u16x8*)&hl[(8 + (t >> 6)) * 520 + (t & 63) * 8] = z;
    }

    // staging: thread t loads 16B of h_t: batch row t>>6, k chunk t&63
    const int srow = t >> 6;
    const int soff = (bg * 8 + srow) * NH + (t & 63) * 8;
    u16* hl_w = &hl[srow * 520 + (t & 63) * 8];

    // post-transpose identities
    const int p = lane & 3;
    const int q = (lane >> 2) & 3;
    const int batg = bg * 8 + (lane >> 4) * 4 + p;
    const int un0 = ubase + q;
    const bool act = lane < 32;
    const bool sl = act && ((lane & 4) == 0);   // even-q lanes store u32 pairs

    const int xoff0 = grow0 * 64 + bg * 8 + (lane >> 4) * 4;
    const int xoff1 = grow1 * 64 + bg * 8 + (lane >> 4) * 4;

    float4 xv0 = {0, 0, 0, 0}, xv1 = {0, 0, 0, 0};
    if (act) {
        xv0 = *(const float4*)&xg[xoff0];
        xv1 = *(const float4*)&xg[xoff1];
    }
    float cA = 0.f, cB = 0.f;

    for (int step = 0; step < NS; ++step) {
        // every wave polls its group's 8 flags (wave blocks until pass)
        if (step > 0 && lane < 8) {
            const u32* fp = &flags[(bg * 8 + lane) * 32];
            while ((int)load_llc(fp) < step) __builtin_amdgcn_s_sleep(1);
        }
        // stage h_t (8KB) from LLC into LDS
        {
            f32x4 hv = load_llc16(&hbuf[(step & 1) * (NB * NH) + soff]);
            *(f32x4*)hl_w = hv;
        }
        __syncthreads();

        // prefetch next step's xg slice (plain loads, overlap MFMA)
        float4 xn0 = {0, 0, 0, 0}, xn1 = {0, 0, 0, 0};
        if (act && step + 1 < NS) {
            const float* xb = &xg[(step + 1) * XG_SSTRIDE];
            xn0 = *(const float4*)&xb[xoff0];
            xn1 = *(const float4*)&xb[xoff1];
        }

        f32x4 a00 = {0, 0, 0, 0}, a01 = {0, 0, 0, 0};
        f32x4 a10 = {0, 0, 0, 0}, a11 = {0, 0, 0, 0};
        #pragma unroll
        for (int kk = 0; kk < 16; ++kk) {
            bf16x8 av = *(const bf16x8*)&hl[j * 520 + kk * 32 + kc8];
            if (kk & 1) {
                a01 = __builtin_amdgcn_mfma_f32_16x16x32_bf16(av, bw0[kk], a01, 0, 0, 0);
                a11 = __builtin_amdgcn_mfma_f32_16x16x32_bf16(av, bw1[kk], a11, 0, 0, 0);
            } else {
                a00 = __builtin_amdgcn_mfma_f32_16x16x32_bf16(av, bw0[kk], a00, 0, 0, 0);
                a10 = __builtin_amdgcn_mfma_f32_16x16x32_bf16(av, bw1[kk], a10, 0, 0, 0);
            }
        }

        float v0[4], v1[4];
        #pragma unroll
        for (int r = 0; r < 4; ++r) {
            v0[r] = a00[r] + a01[r] + (&xv0.x)[r];
            v1[r] = a10[r] + a11[r] + (&xv1.x)[r];
        }
        quad_transpose(v0, p);
        quad_transpose(v1, p);

        float h0 = lstm_cell(v0, cA);
        float h1 = lstm_cell(v1, cB);
        u32 hb0 = f2bf(h0), hb1 = f2bf(h1);
        u32 o0 = (u32)__shfl_xor((int)hb0, 4);
        u32 o1 = (u32)__shfl_xor((int)hb1, 4);
        if (sl) {
            u32 p0 = hb0 | (o0 << 16);
            u32 p1 = hb1 | (o1 << 16);
            u16* hn = hbuf + ((step & 1) ^ 1) * (NB * NH);
            store_llc((u32*)&hn[batg * NH + un0], p0);
            store_llc((u32*)&hn[batg * NH + un0 + 4], p1);
            *(u32*)&hidden[(batg * NS + step) * NH + un0] = p0;
            *(u32*)&hidden[(batg * NS + step) * NH + un0 + 4] = p1;
        }
        xv0 = xn0; xv1 = xn1;
        __syncthreads();   // drains all waves' h stores (vmcnt 0)

        if (step + 1 < NS && t == 0)
            store_llc(&flags[blockIdx.x * 32], (u32)(step + 1));
    }
}

// ------------------------------------- K3: logits = hidden @ W_cls^T + b_cls
__global__ __launch_bounds__(256) void k3_cls(
    const u16* __restrict__ Wc, const u16* __restrict__ hid,
    const float* __restrict__ bcls,
    float* __restrict__ out, float* __restrict__ lse)
{
    __shared__ u16x8 Al8[512];
    __shared__ u16x8 Bl8[512];
    __shared__ float red[2][128];
    u16* Al = (u16*)Al8;
    u16* Bl = (u16*)Bl8;

    const int t = threadIdx.x;
    const int lane = t & 63, w = t >> 6;
    const int wm = w >> 1, wn = w & 1;
    const int vtile = blockIdx.y * 128, mtile = blockIdx.x * 128;

    const int r0 = t >> 2, r1 = r0 + 64, q = t & 3;

    f32x4 acc[4][4];
    for (int i = 0; i < 4; ++i)
        for (int j2 = 0; j2 < 4; ++j2) acc[i][j2] = {0.f, 0.f, 0.f, 0.f};

    const int kc8 = (lane >> 4) * 8;
    for (int kk = 0; kk < 16; ++kk) {
        const int k0 = kk * 32;
        *(u16x8*)&Al[t * 8]         = *(const u16x8*)&Wc[(vtile + r0) * NH + k0 + q * 8];
        *(u16x8*)&Al[(t + 256) * 8] = *(const u16x8*)&Wc[(vtile + r1) * NH + k0 + q * 8];
        *(u16x8*)&Bl[t * 8]         = *(const u16x8*)&hid[(mtile + r0) * NH + k0 + q * 8];
        *(u16x8*)&Bl[(t + 256) * 8] = *(const u16x8*)&hid[(mtile + r1) * NH + k0 + q * 8];
        __syncthreads();
        bf16x8 af[4], bf[4];
        #pragma unroll
        for (int i = 0; i < 4; ++i) {
            af[i] = ld_frag(&Al[(wm * 64 + i * 16 + (lane & 15)) * 32 + kc8]);
            bf[i] = ld_frag(&Bl[(wn * 64 + i * 16 + (lane & 15)) * 32 + kc8]);
        }
        #pragma unroll
        for (int fi = 0; fi < 4; ++fi)
            #pragma unroll
            for (int fj = 0; fj < 4; ++fj)
                acc[fi][fj] = __builtin_amdgcn_mfma_f32_16x16x32_bf16(
                    af[fi], bf[fj], acc[fi][fj], 0, 0, 0);
        __syncthreads();
    }

    float lsum[4] = {0.f, 0.f, 0.f, 0.f};
    #pragma unroll
    for (int fi = 0; fi < 4; ++fi) {
        const int v0 = vtile + wm * 64 + fi * 16 + ((lane >> 4) << 2);
        const bool vok = (v0 < NV);
        float4 bc = {0.f, 0.f, 0.f, 0.f};
        if (vok) bc = *(const float4*)&bcls[v0];
        #pragma unroll
        for (int fj = 0; fj < 4; ++fj) {
            const int m = mtile + wn * 64 + fj * 16 + (lane & 15);
            const int b = m >> 7, s = m & 127;
            if (vok) {
                float* dst = &out[b * OUT_BSTRIDE + v0 * NS + s];
                float e = 0.f;
                #pragma unroll
                for (int r = 0; r < 4; ++r) {
                    float lg = acc[fi][fj][r] + (&bc.x)[r];
                    dst[r * NS] = lg;
                    e += __expf(lg);
                }
                lsum[fj] += e;
            }
        }
    }
    #pragma unroll
    for (int fj = 0; fj < 4; ++fj) {
        lsum[fj] += __shfl_xor(lsum[fj], 16);
        lsum[fj] += __shfl_xor(lsum[fj], 32);
    }
    if (lane < 16) {
        #pragma unroll
        for (int fj = 0; fj < 4; ++fj)
            red[wm][wn * 64 + fj * 16 + lane] = lsum[fj];
    }
    __syncthreads();
    if (t < 128) {
        const int m = mtile + t;
        atomicAdd(&lse[m], red[0][t] + red[1][t]);
    }
}

// ------------------------------------------------------------- K4/K5 epilogue
__global__ void k4_log(const float* __restrict__ lse, float* __restrict__ ll) {
    int i = blockIdx.x * 256 + threadIdx.x;
    if (i < NBS) ll[i] = logf(lse[i]);
}

__global__ void k5_norm(float* __restrict__ out, const float* __restrict__ ll) {
    const int total4 = NB * NV * NS / 4;   // 16,384,000
    float4* o4 = (float4*)out;
    for (int i = blockIdx.x * blockDim.x + threadIdx.x; i < total4;
         i += gridDim.x * blockDim.x) {
        const int i4 = i * 4;
        const int b = i4 / OUT_BSTRIDE;
        const int s = (i4 - b * OUT_BSTRIDE) & 127;
        float4 v = o4[i];
        const float4 l = *(const float4*)&ll[b * NS + s];
        v.x -= l.x; v.y -= l.y; v.z -= l.z; v.w -= l.w;
        o4[i] = v;
    }
}

// ---------------------------------------------------------------------------
extern "C" void kernel_launch(void* const* d_in, const int* in_sizes, int n_in,
                              void* d_out, int out_size, void* d_ws, size_t ws_size,
                              hipStream_t stream) {
    const int*   toks   = (const int*)d_in[0];
    const float* emb_f  = (const float*)d_in[1];
    const float* Wih_f  = (const float*)d_in[2];
    const float* Whh_f  = (const float*)d_in[3];
    const float* bih    = (const float*)d_in[4];
    const float* bhh    = (const float*)d_in[5];
    const float* Wcls_f = (const float*)d_in[6];
    const float* bcls   = (const float*)d_in[7];
    float* out = (float*)d_out;
    char*  ws  = (char*)d_ws;

    // workspace layout (bytes)
    u32*   flags  = (u32*)(ws + 0);            // 8192 (64 x 128B lines)
    float* lse    = (float*)(ws + 8192);       // 32768
    float* loglse = (float*)(ws + 40960);      // 32768
    u16*   hbuf   = (u16*)(ws + 73728);        // 131072
    u16*   embb   = (u16*)(ws + 204800);       // 4,096,000
    u16*   wihb   = (u16*)(ws + 4300800);      // 1,048,576
    u16*   whhb   = (u16*)(ws + 5349376);      // 2,097,152
    u16*   wclsb  = (u16*)(ws + 7446528);      // 8,388,608 (padded 8192 rows)
    u16*   hidden = (u16*)(ws + 15835136);     // 8,388,608

    // x_gates f32 [S][G][B] lives in d_out scratch (16.8M floats < 65.5M)
    float* xg = out;

    hipMemsetAsync(ws, 0, 204800, stream);     // flags + lse + loglse + hbuf
    hipMemsetAsync((char*)wclsb + NV * NH * 2, 0, (NVP - NV) * NH * 2, stream);

    cvt_bf16<<<1024, 256, 0, stream>>>(emb_f,  embb,  NV * NE / 8);
    cvt_bf16<<<256,  256, 0, stream>>>(Wih_f,  wihb,  NG * NE / 8);
    cvt_bf16<<<512,  256, 0, stream>>>(Whh_f,  whhb,  NG * NH / 8);
    cvt_bf16<<<1024, 256, 0, stream>>>(Wcls_f, wclsb, NV * NH / 8);

    k1_xgates<<<dim3(64, 16), 256, 0, stream>>>(wihb, embb, toks, bih, bhh, xg);
    k2_lstm<<<LSTM_NBLK, 512, 0, stream>>>(whhb, xg, hbuf, hidden, flags);
    k3_cls<<<dim3(64, 64), 256, 0, stream>>>(wclsb, hidden, bcls, out, lse);
    k4_log<<<32, 256, 0, stream>>>(lse, loglse);
    k5_norm<<<2048, 256, 0, stream>>>(out, loglse);
}